// Round 15
// baseline (278.680 us; speedup 1.0000x reference)
//
#include <hip/hip_runtime.h>
#include <hip/hip_bf16.h>
#include <math.h>

#define B_ 4
#define S_ 2048
#define D_ 512
#define H_ 8
#define K_ 512
#define F_ 2048
#define NT 8192     // B*S tokens
#define HK 4096     // H*K

typedef __attribute__((ext_vector_type(8))) short bf16x8;
typedef __attribute__((ext_vector_type(4))) float f32x4;
typedef unsigned short u16;

__device__ __forceinline__ float bits2f(u16 b) {
  union { unsigned u; float f; } c; c.u = ((unsigned)b) << 16; return c.f;
}
__device__ __forceinline__ u16 f2bfbits(float f) {
  union { float f; unsigned u; } c; c.f = f;
  unsigned r = c.u + 0x7fffu + ((c.u >> 16) & 1u);
  return (u16)(r >> 16);
}

__device__ __forceinline__ void gload16(const void* g, void* lds) {
  __builtin_amdgcn_global_load_lds(
      (const __attribute__((address_space(1))) unsigned int*)g,
      (__attribute__((address_space(3))) unsigned int*)lds, 16, 0, 0);
}

// ---------------------------------------------------------------------------
// Preprocessing in ONE launch (r12-proven version):
//   0..2047      : Wo [HK][D] -> transpose -> wot [D][HK]
//   2048..3071   : W1 [D][F]  -> w1t [F][D]
//   3072..4095   : W2 [F][D]  -> w2t [D][F]
//   4096..6143   : Wq f32 -> bf16   wq_nt [D][HK]
//   6144..8191   : Wk f32 -> bf16   wk_nt [D][HK]
//   8192..10239  : Wv f32 -> bf16   wv_nt [D][HK]
//   10240..14335 : x  f32 -> bf16   xb [NT][D]
//   14336..15359 : biascat: [0..4095]=0, [4096+o]=sum_k bv[h,k]*Wo[(h,k),d']
// ---------------------------------------------------------------------------
__global__ __launch_bounds__(256) void prep_all(
    const float* __restrict__ Wq, const float* __restrict__ Wk,
    const float* __restrict__ Wv, const float* __restrict__ Wo,
    const float* __restrict__ W1, const float* __restrict__ W2,
    const float* __restrict__ bv, const float* __restrict__ x,
    u16* __restrict__ wq_nt, u16* __restrict__ wk_nt,
    u16* __restrict__ wv_nt, u16* __restrict__ wot,
    u16* __restrict__ w1t, u16* __restrict__ w2t,
    float* __restrict__ biascat, u16* __restrict__ xb) {
  const int id = blockIdx.x;
  const int tid = threadIdx.x;
  __shared__ float tile[32][33];
  if (id < 4096) {                       // 32x32 transposes
    const int tx = tid & 31;
    const int ty = tid >> 5;
    const float* src; u16* dst;
    int rb, cb, ldin, ldout;
    if (id < 2048) {        // Wo
      int rem = id; rb = (rem >> 4) * 32; cb = (rem & 15) * 32;
      src = Wo; ldin = D_; dst = wot; ldout = HK;
    } else if (id < 3072) { // W1
      int rem = id - 2048; rb = (rem & 15) * 32; cb = (rem >> 4) * 32;
      src = W1; ldin = F_; dst = w1t; ldout = D_;
    } else {                // W2
      int rem = id - 3072; rb = (rem >> 4) * 32; cb = (rem & 15) * 32;
      src = W2; ldin = D_; dst = w2t; ldout = F_;
    }
    for (int i = ty; i < 32; i += 8)
      tile[i][tx] = src[(size_t)(rb + i) * ldin + cb + tx];
    __syncthreads();
    for (int i = ty; i < 32; i += 8)
      dst[(size_t)(cb + i) * ldout + rb + tx] = f2bfbits(tile[tx][i]);
  } else if (id < 14336) {               // f32 -> bf16 converts
    const float* s; u16* d; int base;
    if (id < 6144)       { s = Wq; d = wq_nt; base = id - 4096; }
    else if (id < 8192)  { s = Wk; d = wk_nt; base = id - 6144; }
    else if (id < 10240) { s = Wv; d = wv_nt; base = id - 8192; }
    else                 { s = x;  d = xb;    base = id - 10240; }
    int i = base * 256 + tid;
    float4 f = ((const float4*)s)[i];
    ushort4 o;
    o.x = f2bfbits(f.x); o.y = f2bfbits(f.y);
    o.z = f2bfbits(f.z); o.w = f2bfbits(f.w);
    ((ushort4*)d)[i] = o;
  } else {                               // cbias: one wave per out column
    const int lane = tid & 63;
    const int out = (id - 14336) * 4 + (tid >> 6);   // [0,4096)
    const int h = out >> 9, dp = out & 511;
    float a = 0.f;
#pragma unroll
    for (int i = 0; i < 8; ++i) {
      const int k = lane * 8 + i;
      a += bv[h * 512 + k] * Wo[(size_t)(h * 512 + k) * D_ + dp];
    }
    for (int m = 32; m >= 1; m >>= 1) a += __shfl_xor(a, m);
    if (lane == 0) {
      biascat[4096 + out] = a;
      biascat[out] = 0.f;
    }
  }
}

// ---------------------------------------------------------------------------
// bf16 GEMM, 128x128 tile, BK=64, 4 waves, dbuf LDS, counted-vmcnt 2-phase
// (r12-proven). T2 XOR swizzle via pre-swizzled global source (rule 21).
// SCORES=1 (YZ): blocks with bn<4096 hold a 128x128 Y-slice in acc; instead
//   of storing, stage x[bm-1..bm+128, c0..c0+128) in LDS (stride 136 u16:
//   16B-aligned rows, lane-groups spread 2-way) and accumulate the 3 band
//   dots per row via per-thread FMA + 16-lane shfl reduce + atomicAdd into
//   scores[t][h][4] (f32, 8 adds/entry). Blocks with bn>=4096 store Z to
//   Cb at ldc with col-4096. Edge rows clamped (attn_ln masks by s).
// BATCH=1: blockIdx.z = batch (A/Bt or A2/Bt2 per zsplit); Cb += z*cZ.
// BATCH=0: blockIdx.z = split-K slice (k0 = z*kslice, Cf += z*zstride).
// OUTBF=1: bf16 store (+bias)(+gelu);  OUTBF=0: f32 store, row stride ldc.
// ---------------------------------------------------------------------------
template <int BIAS, int GELU, int OUTBF, int BATCH, int SCORES>
__global__ __launch_bounds__(256) void gemm128d(const u16* __restrict__ A, int lda,
                                                size_t aZ,
                                                const u16* __restrict__ Bt, int ldb,
                                                size_t bZ,
                                                const u16* __restrict__ A2,
                                                const u16* __restrict__ Bt2,
                                                int zsplit,
                                                const float* __restrict__ bias,
                                                float* __restrict__ Cf, size_t zstride,
                                                u16* __restrict__ Cb, int ldc,
                                                size_t cZ, int kslice,
                                                const u16* __restrict__ xb2,
                                                float* __restrict__ scores) {
  __shared__ short lds[2][16384];   // per buf: A[128][64] @0, B[128][64] @8192
  const int tid = threadIdx.x;
  const int lane = tid & 63;
  const int wave = tid >> 6;
  const int bm = blockIdx.x * 128;
  const int bn = blockIdx.y * 128;
  const int z = blockIdx.z;
  const int k0 = BATCH ? 0 : z * kslice;
  if (BATCH) {
    if (z < zsplit) { A += (size_t)z * aZ; Bt += (size_t)z * bZ; }
    else { A = A2 + (size_t)(z - zsplit) * aZ; Bt = Bt2 + (size_t)(z - zsplit) * bZ; }
  }

  const int wr = (wave >> 1) * 64;
  const int wc = (wave & 1) * 64;

  f32x4 acc[4][4] = {};

  const int srow = wave * 8 + (lane >> 3);
  const int scol = ((lane & 7) ^ (lane >> 3)) * 8;    // swizzled source col
  const u16* ag = A + (size_t)(bm + srow) * lda + scol;
  const u16* bg = Bt + (size_t)(bn + srow) * ldb + scol;
  const int ldsbase = wave * 8 * 64;

  auto STAGE = [&](int buf, int kt) {
    short* sA = &lds[buf][0];
    short* sB = &lds[buf][8192];
#pragma unroll
    for (int r = 0; r < 4; ++r)
      gload16(ag + (size_t)(r * 32) * lda + kt, sA + ldsbase + r * 32 * 64);
#pragma unroll
    for (int r = 0; r < 4; ++r)
      gload16(bg + (size_t)(r * 32) * ldb + kt, sB + ldsbase + r * 32 * 64);
  };

  auto COMPUTE = [&](int buf) {
    const short* sA = &lds[buf][0];
    const short* sB = &lds[buf][8192];
#pragma unroll
    for (int ks = 0; ks < 2; ++ks) {
      const int kos = (ks * 32 + (lane >> 4) * 8) ^ ((lane & 7) << 3);
      bf16x8 a[4], b[4];
#pragma unroll
      for (int m = 0; m < 4; ++m)
        a[m] = *(const bf16x8*)&sA[(wr + m * 16 + (lane & 15)) * 64 + kos];
#pragma unroll
      for (int n = 0; n < 4; ++n)
        b[n] = *(const bf16x8*)&sB[(wc + n * 16 + (lane & 15)) * 64 + kos];
#pragma unroll
      for (int m = 0; m < 4; ++m)
#pragma unroll
        for (int n = 0; n < 4; ++n)
          acc[m][n] = __builtin_amdgcn_mfma_f32_16x16x32_bf16(a[m], b[n], acc[m][n], 0, 0, 0);
    }
  };

  const int nt = kslice >> 6;
  STAGE(0, k0);
  int cur = 0;
  for (int t = 0; t < nt; ++t) {
    if (t + 1 < nt) {
      STAGE(cur ^ 1, k0 + (t + 1) * 64);               // prefetch next tile
      asm volatile("s_waitcnt vmcnt(8)" ::: "memory"); // retire tile t only
    } else {
      asm volatile("s_waitcnt vmcnt(0)" ::: "memory"); // tail: all retired
    }
    asm volatile("s_barrier" ::: "memory");            // tile t visible to all
    COMPUTE(cur);
    if (t + 1 < nt)
      asm volatile("s_barrier" ::: "memory");          // write-safety for next STAGE
    cur ^= 1;
  }

  if (SCORES && bn < 4096) {
    // ---- Y-slice -> band-score partials (no C store) ----
    __syncthreads();                    // all waves done reading LDS bufs
    u16* xs = (u16*)&lds[0][0];         // [130][136] u16 (35.4 KB)
    const int c0 = bn & 511;
    for (int i = tid; i < 130 * 16; i += 256) {
      const int rrow = i >> 4, chunk = i & 15;
      int grow = bm - 1 + rrow;
      grow = grow < 0 ? 0 : (grow > NT - 1 ? NT - 1 : grow);
      *(bf16x8*)&xs[rrow * 136 + chunk * 8] =
          *(const bf16x8*)&xb2[(size_t)grow * 512 + c0 + chunk * 8];
    }
    __syncthreads();
    const int h = bn >> 9;
#pragma unroll
    for (int m = 0; m < 4; ++m) {
#pragma unroll
      for (int r = 0; r < 4; ++r) {
        const int lt = wr + m * 16 + ((lane >> 4) << 2) + r;   // 0..127
        float pj0 = 0.f, pj1 = 0.f, pj2 = 0.f;
#pragma unroll
        for (int n = 0; n < 4; ++n) {
          const float av = acc[m][n][r];
          const int lcol = wc + n * 16 + (lane & 15);
          pj0 += av * bits2f(xs[(lt + 0) * 136 + lcol]);
          pj1 += av * bits2f(xs[(lt + 1) * 136 + lcol]);
          pj2 += av * bits2f(xs[(lt + 2) * 136 + lcol]);
        }
#pragma unroll
        for (int msk = 1; msk <= 8; msk <<= 1) {
          pj0 += __shfl_xor(pj0, msk);
          pj1 += __shfl_xor(pj1, msk);
          pj2 += __shfl_xor(pj2, msk);
        }
        if ((lane & 15) == 0) {
          float* sc = &scores[(((size_t)(bm + lt)) * 8 + h) * 4];
          atomicAdd(&sc[0], pj0);
          atomicAdd(&sc[1], pj1);
          atomicAdd(&sc[2], pj2);
        }
      }
    }
    return;
  }

  float* Cfz = Cf + (BATCH ? 0 : (size_t)z * zstride);
  u16* Cbz = Cb + (BATCH ? (size_t)z * cZ : 0);
#pragma unroll
  for (int m = 0; m < 4; ++m) {
    const int row0 = bm + wr + m * 16 + (lane >> 4) * 4;
#pragma unroll
    for (int n = 0; n < 4; ++n) {
      const int col = bn + wc + n * 16 + (lane & 15);
      float badd = BIAS ? bias[col] : 0.f;
      f32x4 a4 = acc[m][n];
#pragma unroll
      for (int r = 0; r < 4; ++r) {
        float vv = a4[r] + badd;
        if (GELU) vv = 0.5f * vv * (1.f + erff(vv * 0.70710678118f));
        const int row = row0 + r;
        if (OUTBF) Cbz[(size_t)row * ldc + (SCORES ? col - 4096 : col)] = f2bfbits(vv);
        else Cfz[(size_t)row * ldc + col] = vv;
      }
    }
  }
}

// ---------------------------------------------------------------------------
// Band attention + residual + LN1 (scores precomputed by YZ epilogue):
// one block per token t, T1 XCD-chunked (t = (b&7)*1024 + b>>3).
// zbuf row t (4096 u16): Z[t] = x@G_h + c_h.  attn[t,d] =
// sum_j sum_h p_j[t,h]·Z[t+j-1,h,d];  then y = x + attn + bo; LN -> out1.
// ---------------------------------------------------------------------------
__global__ __launch_bounds__(256) void attn_ln(
    const u16* __restrict__ zbuf, const float* __restrict__ scores,
    const float* __restrict__ xres, const float* __restrict__ bo,
    const float* __restrict__ g1, const float* __restrict__ be1,
    float* __restrict__ out1f, u16* __restrict__ out1b) {
  const int t = ((blockIdx.x & 7) << 10) | (blockIdx.x >> 3);  // XCD-chunked
  const int s = t & (S_ - 1);
  const int tid = threadIdx.x;
  const int lane = tid & 63;
  const int wave = tid >> 6;
  __shared__ float sP[8][3];
  __shared__ float red[8];

  if (tid < 8) {
    const float scale = 0.044194173824159f;  // 1/sqrt(512)
    float4 sc = *(const float4*)&scores[((size_t)t * 8 + tid) * 4];
    const bool v0 = (s > 0), v2 = (s < S_ - 1);
    float s0 = v0 ? sc.x * scale : -1e30f;
    float s1 = sc.y * scale;
    float s2 = v2 ? sc.z * scale : -1e30f;
    float mx = fmaxf(s0, fmaxf(s1, s2));
    float p0 = v0 ? expf(s0 - mx) : 0.f;
    float p1 = expf(s1 - mx);
    float p2 = v2 ? expf(s2 - mx) : 0.f;
    float inv = 1.f / (p0 + p1 + p2);
    sP[tid][0] = p0 * inv; sP[tid][1] = p1 * inv; sP[tid][2] = p2 * inv;
  }
  __syncthreads();
  // stencil over Z: thread tid -> output dims d0, d0+1
  const int d0 = tid * 2;
  const int tm = t - (s > 0 ? 1 : 0);
  const int tp = t + (s < S_ - 1 ? 1 : 0);
  const int trow[3] = {tm, t, tp};
  float a0 = 0.f, a1 = 0.f;
#pragma unroll
  for (int j = 0; j < 3; ++j) {
    const u16* zr = zbuf + (size_t)trow[j] * 4096;
#pragma unroll
    for (int h = 0; h < 8; ++h) {
      const float p = sP[h][j];
      unsigned zz = *(const unsigned*)&zr[h * 512 + d0];
      a0 += p * bits2f((u16)(zz & 0xffffu));
      a1 += p * bits2f((u16)(zz >> 16));
    }
  }
  // residual + bo, then LN over the 512-dim row held across the block
  const size_t base = (size_t)t * D_;
  float2 xv = ((const float2*)(xres + base))[tid];
  float2 bv2 = ((const float2*)bo)[tid];
  float y0 = xv.x + a0 + bv2.x;
  float y1 = xv.y + a1 + bv2.y;
  float sum = y0 + y1, ssum = y0 * y0 + y1 * y1;
  for (int m = 32; m >= 1; m >>= 1) {
    sum += __shfl_xor(sum, m); ssum += __shfl_xor(ssum, m);
  }
  if (lane == 0) { red[wave] = sum; red[4 + wave] = ssum; }
  __syncthreads();
  sum = red[0] + red[1] + red[2] + red[3];
  ssum = red[4] + red[5] + red[6] + red[7];
  const float mean = sum * (1.f / D_);
  const float var = ssum * (1.f / D_) - mean * mean;
  const float rstd = rsqrtf(var + 1e-3f);
  float2 gv = ((const float2*)g1)[tid];
  float2 bev = ((const float2*)be1)[tid];
  float o0 = (y0 - mean) * rstd * gv.x + bev.x;
  float o1 = (y1 - mean) * rstd * gv.y + bev.y;
  float2 of; of.x = o0; of.y = o1;
  ((float2*)(out1f + base))[tid] = of;
  ushort2 ob; ob.x = f2bfbits(o0); ob.y = f2bfbits(o1);
  ((ushort2*)(out1b + base))[tid] = ob;
}

// ---------------------------------------------------------------------------
// y = xres + sum_p parts[p] (+bias); out = LN(y)*gamma+beta -> fp32 / bf16
// ---------------------------------------------------------------------------
__global__ __launch_bounds__(256) void resid_ln(const float* __restrict__ xres,
                                                const float* __restrict__ parts,
                                                int nparts, size_t pstride,
                                                size_t prowstride,
                                                const float* __restrict__ bias,
                                                const float* __restrict__ gamma,
                                                const float* __restrict__ beta,
                                                float* __restrict__ outf,
                                                u16* __restrict__ outb) {
  const int row = blockIdx.x;
  const int tid = threadIdx.x;
  const size_t base = (size_t)row * D_;
  float2 xv = ((const float2*)(xres + base))[tid];
  float y0 = xv.x, y1 = xv.y;
  for (int p = 0; p < nparts; ++p) {
    const float* pr = parts + p * pstride + (size_t)row * prowstride;
    float2 pv = ((const float2*)pr)[tid];
    y0 += pv.x; y1 += pv.y;
  }
  if (bias) {
    float2 bv = ((const float2*)bias)[tid];
    y0 += bv.x; y1 += bv.y;
  }
  float s = y0 + y1, ss = y0 * y0 + y1 * y1;
  for (int m = 32; m >= 1; m >>= 1) { s += __shfl_xor(s, m); ss += __shfl_xor(ss, m); }
  __shared__ float red[8];
  const int wave = tid >> 6, lane = tid & 63;
  if (lane == 0) { red[wave] = s; red[4 + wave] = ss; }
  __syncthreads();
  s = red[0] + red[1] + red[2] + red[3];
  ss = red[4] + red[5] + red[6] + red[7];
  const float mean = s * (1.f / D_);
  const float var = ss * (1.f / D_) - mean * mean;
  const float rstd = rsqrtf(var + 1e-3f);
  float2 gv = ((const float2*)gamma)[tid];
  float2 bev = ((const float2*)beta)[tid];
  float o0 = (y0 - mean) * rstd * gv.x + bev.x;
  float o1 = (y1 - mean) * rstd * gv.y + bev.y;
  if (outf) { float2 of; of.x = o0; of.y = o1; ((float2*)(outf + base))[tid] = of; }
  if (outb) { ushort2 ob; ob.x = f2bfbits(o0); ob.y = f2bfbits(o1); ((ushort2*)(outb + base))[tid] = ob; }
}

// ---------------------------------------------------------------------------
extern "C" void kernel_launch(void* const* d_in, const int* in_sizes, int n_in,
                              void* d_out, int out_size, void* d_ws, size_t ws_size,
                              hipStream_t stream) {
  const float* x  = (const float*)d_in[0];
  const float* Wq = (const float*)d_in[1];
  const float* Wk = (const float*)d_in[3];
  const float* Wv = (const float*)d_in[5];
  const float* bv = (const float*)d_in[6];
  const float* Wo = (const float*)d_in[7];
  const float* bo = (const float*)d_in[8];
  const float* W1 = (const float*)d_in[9];
  const float* b1 = (const float*)d_in[10];
  const float* W2 = (const float*)d_in[11];
  const float* b2 = (const float*)d_in[12];
  const float* g1 = (const float*)d_in[13];
  const float* be1 = (const float*)d_in[14];
  const float* g2 = (const float*)d_in[15];
  const float* be2 = (const float*)d_in[16];
  float* out = (float*)d_out;

  char* w = (char*)d_ws;
  size_t o = 0;
  auto nxt = [&](size_t bytes) -> char* {
    char* p = w + o;
    o += (bytes + 255) & ~(size_t)255;
    return p;
  };
  u16* xb     = (u16*)nxt((size_t)NT * D_ * 2);        // 8.4MB
  u16* wq_nt  = (u16*)nxt((size_t)D_ * HK * 2);        // 4.2MB [D][HK]
  u16* wk_nt  = (u16*)nxt((size_t)D_ * HK * 2);        // 4.2MB
  u16* wv_nt  = (u16*)nxt((size_t)D_ * HK * 2);        // 4.2MB
  u16* wot    = (u16*)nxt((size_t)D_ * HK * 2);        // 4.2MB
  u16* w1t    = (u16*)nxt((size_t)F_ * D_ * 2);        // 2.1MB
  u16* w2t    = (u16*)nxt((size_t)D_ * F_ * 2);        // 2.1MB
  u16* mg     = (u16*)nxt((size_t)8192 * 512 * 2);     // 8.4MB [M^T | G^T]
  float* biascat = (float*)nxt((size_t)8192 * 4);
  float* scores  = (float*)nxt((size_t)NT * H_ * 4 * 4);  // 1MB [t][h][4]
  u16* zbuf   = (u16*)nxt((size_t)NT * 4096 * 2);      // 67.1MB Z only
  float* out1f = (float*)nxt((size_t)NT * D_ * 4);     // 16.8MB
  u16* out1b   = (u16*)nxt((size_t)NT * D_ * 2);       // 8.4MB
  // aliases inside zbuf (live ranges disjoint):
  u16* hb = (u16*)zbuf;                                // FFN1 out, 33.6MB
  float* ffnP = (float*)((char*)zbuf + 33554432);      // FFN2 partials 2x16.8MB

  // --- scores zero-init (accumulated via atomicAdd in YZ epilogue) ---
  hipMemsetAsync(scores, 0, (size_t)NT * H_ * 4 * 4, stream);

  // --- prep: transposes + converts + cbias (one launch, r12 version) ---
  prep_all<<<dim3(15360), 256, 0, stream>>>(Wq, Wk, Wv, Wo, W1, W2, bv, x,
                                            wq_nt, wk_nt, wv_nt, wot, w1t, w2t,
                                            biascat, xb);

  // --- MG-pre (16 batched 512^3):
  //  z<8:  mg[z*512+d'][d]  = sum_k Wk[d',(z,k)]·Wq[d,(z,k)]   (M_h^T)
  //  z>=8: mg[z*512+d'][d]  = sum_k Wo[(h,k),d']·Wv[d,(h,k)]   (G_h^T)
  gemm128d<0, 0, 1, 1, 0><<<dim3(4, 4, 16), 256, 0, stream>>>(
      wk_nt, HK, 512, wq_nt, HK, 512, wot, wv_nt, 8,
      nullptr, nullptr, 0, mg, 512, (size_t)512 * 512, 512, nullptr, nullptr);

  // --- YZ: Y-blocks -> band-score partials (atomicAdd into scores);
  //         Z-blocks -> zbuf = x@G_h + c  (one N=8192 GEMM) ---
  gemm128d<1, 0, 1, 0, 1><<<dim3(64, 64, 1), 256, 0, stream>>>(
      xb, D_, 0, mg, 512, 0, nullptr, nullptr, 0, biascat,
      nullptr, 0, zbuf, 4096, 0, 512, xb, scores);

  // --- attn + residual + LN1 fused -> out1f / out1b (XCD-chunked t) ---
  attn_ln<<<dim3(NT), 256, 0, stream>>>(zbuf, scores, x, bo, g1, be1,
                                        out1f, out1b);

  // --- FFN1: hb = gelu(out1 @ W1 + b1) ---
  gemm128d<1, 1, 1, 0, 0><<<dim3(64, 16, 1), 256, 0, stream>>>(
      out1b, D_, 0, w1t, D_, 0, nullptr, nullptr, 0, b1,
      nullptr, 0, hb, F_, 0, 512, nullptr, nullptr);

  // --- FFN2: ffnP[z] = hb @ W2 (split-K=2; b2 folded into LN2) ---
  gemm128d<0, 0, 0, 0, 0><<<dim3(64, 4, 2), 256, 0, stream>>>(
      hb, F_, 0, w2t, F_, 0, nullptr, nullptr, 0, nullptr,
      ffnP, (size_t)NT * D_, nullptr, D_, 0, 1024, nullptr, nullptr);

  // --- LN2: out = LN(out1 + ffn + b2) ---
  resid_ln<<<dim3(NT), 256, 0, stream>>>(out1f, ffnP, 2, (size_t)NT * D_, D_, b2,
                                         g2, be2, out, nullptr);

  (void)in_sizes; (void)n_in; (void)out_size; (void)ws_size;
}

// Round 16
// 246.190 us; speedup vs baseline: 1.1320x; 1.1320x over previous
//
#include <hip/hip_runtime.h>
#include <hip/hip_bf16.h>
#include <math.h>

#define B_ 4
#define S_ 2048
#define D_ 512
#define H_ 8
#define K_ 512
#define F_ 2048
#define NT 8192     // B*S tokens
#define HK 4096     // H*K

typedef __attribute__((ext_vector_type(8))) short bf16x8;
typedef __attribute__((ext_vector_type(4))) float f32x4;
typedef unsigned short u16;

__device__ __forceinline__ float bits2f(u16 b) {
  union { unsigned u; float f; } c; c.u = ((unsigned)b) << 16; return c.f;
}
__device__ __forceinline__ u16 f2bfbits(float f) {
  union { float f; unsigned u; } c; c.f = f;
  unsigned r = c.u + 0x7fffu + ((c.u >> 16) & 1u);
  return (u16)(r >> 16);
}

__device__ __forceinline__ void gload16(const void* g, void* lds) {
  __builtin_amdgcn_global_load_lds(
      (const __attribute__((address_space(1))) unsigned int*)g,
      (__attribute__((address_space(3))) unsigned int*)lds, 16, 0, 0);
}

// fast GELU (tanh form): |err| < 3e-3 abs; ~7 VALU ops vs erff's ~20.
__device__ __forceinline__ float fast_gelu(float v) {
  float u = 1.5957691216f * (v + 0.044715f * v * v * v);  // 2*0.79788456*(...)
  float e = __expf(u);
  return v * e / (e + 1.f);   // 0.5v(1+tanh(u/2)) == v*e^u/(e^u+1)
}

// ---------------------------------------------------------------------------
// Preprocessing in ONE launch (r12-proven version):
//   0..2047      : Wo [HK][D] -> transpose -> wot [D][HK]
//   2048..3071   : W1 [D][F]  -> w1t [F][D]
//   3072..4095   : W2 [F][D]  -> w2t [D][F]
//   4096..6143   : Wq f32 -> bf16   wq_nt [D][HK]
//   6144..8191   : Wk f32 -> bf16   wk_nt [D][HK]
//   8192..10239  : Wv f32 -> bf16   wv_nt [D][HK]
//   10240..14335 : x  f32 -> bf16   xb [NT][D]
//   14336..15359 : biascat: [0..4095]=0, [4096+o]=sum_k bv[h,k]*Wo[(h,k),d']
// ---------------------------------------------------------------------------
__global__ __launch_bounds__(256) void prep_all(
    const float* __restrict__ Wq, const float* __restrict__ Wk,
    const float* __restrict__ Wv, const float* __restrict__ Wo,
    const float* __restrict__ W1, const float* __restrict__ W2,
    const float* __restrict__ bv, const float* __restrict__ x,
    u16* __restrict__ wq_nt, u16* __restrict__ wk_nt,
    u16* __restrict__ wv_nt, u16* __restrict__ wot,
    u16* __restrict__ w1t, u16* __restrict__ w2t,
    float* __restrict__ biascat, u16* __restrict__ xb) {
  const int id = blockIdx.x;
  const int tid = threadIdx.x;
  __shared__ float tile[32][33];
  if (id < 4096) {                       // 32x32 transposes
    const int tx = tid & 31;
    const int ty = tid >> 5;
    const float* src; u16* dst;
    int rb, cb, ldin, ldout;
    if (id < 2048) {        // Wo
      int rem = id; rb = (rem >> 4) * 32; cb = (rem & 15) * 32;
      src = Wo; ldin = D_; dst = wot; ldout = HK;
    } else if (id < 3072) { // W1
      int rem = id - 2048; rb = (rem & 15) * 32; cb = (rem >> 4) * 32;
      src = W1; ldin = F_; dst = w1t; ldout = D_;
    } else {                // W2
      int rem = id - 3072; rb = (rem >> 4) * 32; cb = (rem & 15) * 32;
      src = W2; ldin = D_; dst = w2t; ldout = F_;
    }
    for (int i = ty; i < 32; i += 8)
      tile[i][tx] = src[(size_t)(rb + i) * ldin + cb + tx];
    __syncthreads();
    for (int i = ty; i < 32; i += 8)
      dst[(size_t)(cb + i) * ldout + rb + tx] = f2bfbits(tile[tx][i]);
  } else if (id < 14336) {               // f32 -> bf16 converts
    const float* s; u16* d; int base;
    if (id < 6144)       { s = Wq; d = wq_nt; base = id - 4096; }
    else if (id < 8192)  { s = Wk; d = wk_nt; base = id - 6144; }
    else if (id < 10240) { s = Wv; d = wv_nt; base = id - 8192; }
    else                 { s = x;  d = xb;    base = id - 10240; }
    int i = base * 256 + tid;
    float4 f = ((const float4*)s)[i];
    ushort4 o;
    o.x = f2bfbits(f.x); o.y = f2bfbits(f.y);
    o.z = f2bfbits(f.z); o.w = f2bfbits(f.w);
    ((ushort4*)d)[i] = o;
  } else {                               // cbias: one wave per out column
    const int lane = tid & 63;
    const int out = (id - 14336) * 4 + (tid >> 6);   // [0,4096)
    const int h = out >> 9, dp = out & 511;
    float a = 0.f;
#pragma unroll
    for (int i = 0; i < 8; ++i) {
      const int k = lane * 8 + i;
      a += bv[h * 512 + k] * Wo[(size_t)(h * 512 + k) * D_ + dp];
    }
    for (int m = 32; m >= 1; m >>= 1) a += __shfl_xor(a, m);
    if (lane == 0) {
      biascat[4096 + out] = a;
      biascat[out] = 0.f;
    }
  }
}

// ---------------------------------------------------------------------------
// bf16 GEMM, 128x128 tile, BK=64, 4 waves, dbuf LDS, counted-vmcnt 2-phase
// (r12-proven): STAGE(t+1); vmcnt(8); s_barrier; COMPUTE(t); s_barrier.
// T2 XOR swizzle via pre-swizzled global source (rule 21), 0-conflict.
// BATCH=1: blockIdx.z = batch (A/Bt or A2/Bt2 per zsplit); Cb += z*cZ.
// BATCH=0: blockIdx.z = split-K slice (k0 = z*kslice, Cf += z*zstride).
// OUTBF=1: bf16 store (+bias)(+gelu);  OUTBF=0: f32 store, row stride ldc.
// ---------------------------------------------------------------------------
template <int BIAS, int GELU, int OUTBF, int BATCH>
__global__ __launch_bounds__(256) void gemm128d(const u16* __restrict__ A, int lda,
                                                size_t aZ,
                                                const u16* __restrict__ Bt, int ldb,
                                                size_t bZ,
                                                const u16* __restrict__ A2,
                                                const u16* __restrict__ Bt2,
                                                int zsplit,
                                                const float* __restrict__ bias,
                                                float* __restrict__ Cf, size_t zstride,
                                                u16* __restrict__ Cb, int ldc,
                                                size_t cZ, int kslice) {
  __shared__ short lds[2][16384];   // per buf: A[128][64] @0, B[128][64] @8192
  const int tid = threadIdx.x;
  const int lane = tid & 63;
  const int wave = tid >> 6;
  const int bm = blockIdx.x * 128;
  const int bn = blockIdx.y * 128;
  const int z = blockIdx.z;
  const int k0 = BATCH ? 0 : z * kslice;
  if (BATCH) {
    if (z < zsplit) { A += (size_t)z * aZ; Bt += (size_t)z * bZ; }
    else { A = A2 + (size_t)(z - zsplit) * aZ; Bt = Bt2 + (size_t)(z - zsplit) * bZ; }
  }

  const int wr = (wave >> 1) * 64;
  const int wc = (wave & 1) * 64;

  f32x4 acc[4][4] = {};

  const int srow = wave * 8 + (lane >> 3);
  const int scol = ((lane & 7) ^ (lane >> 3)) * 8;    // swizzled source col
  const u16* ag = A + (size_t)(bm + srow) * lda + scol;
  const u16* bg = Bt + (size_t)(bn + srow) * ldb + scol;
  const int ldsbase = wave * 8 * 64;

  auto STAGE = [&](int buf, int kt) {
    short* sA = &lds[buf][0];
    short* sB = &lds[buf][8192];
#pragma unroll
    for (int r = 0; r < 4; ++r)
      gload16(ag + (size_t)(r * 32) * lda + kt, sA + ldsbase + r * 32 * 64);
#pragma unroll
    for (int r = 0; r < 4; ++r)
      gload16(bg + (size_t)(r * 32) * ldb + kt, sB + ldsbase + r * 32 * 64);
  };

  auto COMPUTE = [&](int buf) {
    const short* sA = &lds[buf][0];
    const short* sB = &lds[buf][8192];
#pragma unroll
    for (int ks = 0; ks < 2; ++ks) {
      const int kos = (ks * 32 + (lane >> 4) * 8) ^ ((lane & 7) << 3);
      bf16x8 a[4], b[4];
#pragma unroll
      for (int m = 0; m < 4; ++m)
        a[m] = *(const bf16x8*)&sA[(wr + m * 16 + (lane & 15)) * 64 + kos];
#pragma unroll
      for (int n = 0; n < 4; ++n)
        b[n] = *(const bf16x8*)&sB[(wc + n * 16 + (lane & 15)) * 64 + kos];
#pragma unroll
      for (int m = 0; m < 4; ++m)
#pragma unroll
        for (int n = 0; n < 4; ++n)
          acc[m][n] = __builtin_amdgcn_mfma_f32_16x16x32_bf16(a[m], b[n], acc[m][n], 0, 0, 0);
    }
  };

  const int nt = kslice >> 6;
  STAGE(0, k0);
  int cur = 0;
  for (int t = 0; t < nt; ++t) {
    if (t + 1 < nt) {
      STAGE(cur ^ 1, k0 + (t + 1) * 64);               // prefetch next tile
      asm volatile("s_waitcnt vmcnt(8)" ::: "memory"); // retire tile t only
    } else {
      asm volatile("s_waitcnt vmcnt(0)" ::: "memory"); // tail: all retired
    }
    asm volatile("s_barrier" ::: "memory");            // tile t visible to all
    COMPUTE(cur);
    if (t + 1 < nt)
      asm volatile("s_barrier" ::: "memory");          // write-safety for next STAGE
    cur ^= 1;
  }

  float* Cfz = Cf + (BATCH ? 0 : (size_t)z * zstride);
  u16* Cbz = Cb + (BATCH ? (size_t)z * cZ : 0);
#pragma unroll
  for (int m = 0; m < 4; ++m) {
    const int row0 = bm + wr + m * 16 + (lane >> 4) * 4;
#pragma unroll
    for (int n = 0; n < 4; ++n) {
      const int col = bn + wc + n * 16 + (lane & 15);
      float badd = BIAS ? bias[col] : 0.f;
      f32x4 a4 = acc[m][n];
#pragma unroll
      for (int r = 0; r < 4; ++r) {
        float vv = a4[r] + badd;
        if (GELU) vv = fast_gelu(vv);
        const int row = row0 + r;
        if (OUTBF) Cbz[(size_t)row * ldc + col] = f2bfbits(vv);
        else Cfz[(size_t)row * ldc + col] = vv;
      }
    }
  }
}

// ---------------------------------------------------------------------------
// Band attention + residual + LN1, fully fused: one block per token t.
// T1 XCD swizzle: t = (b&7)*1024 + b>>3 — 1024 consecutive tokens per XCD,
// so Z[t-1],Z[t+1] and x[t±1] neighbor reads hit the XCD-local L2.
// yz row t (8192 u16): cols 0..4095 = Y[t] = x@M_h, cols 4096..8191 =
// Z[t] = x@G_h + c_h.  score(t,t') = Y[t,h]·x[t'];
// attn[t,d] = sum_j sum_h p_j[t,h]·Z[t+j-1,h,d].
// Then y = x[t] + attn + bo; out1 = LN(y)*g1+be1 -> out1f (f32) + out1b (bf16).
// No writes to yz (read-only) -> no cross-block hazard.
// ---------------------------------------------------------------------------
__global__ __launch_bounds__(256) void attn_ln(
    const u16* __restrict__ yz, const u16* __restrict__ xb,
    const float* __restrict__ xres, const float* __restrict__ bo,
    const float* __restrict__ g1, const float* __restrict__ be1,
    float* __restrict__ out1f, u16* __restrict__ out1b) {
  const int t = ((blockIdx.x & 7) << 10) | (blockIdx.x >> 3);  // XCD-chunked
  const int s = t & (S_ - 1);
  const int tid = threadIdx.x;
  const int lane = tid & 63;
  const int wave = tid >> 6;
  __shared__ float sSc[8][3];
  __shared__ float sP[8][3];
  __shared__ float red[8];
  const u16* yrow = yz + (size_t)t * 8192;

  // 24 dots (h in 8, j in 3): wave w computes didx = 6w..6w+5
#pragma unroll
  for (int i = 0; i < 6; ++i) {
    const int didx = wave * 6 + i;
    const int h = didx / 3, j = didx % 3;
    const bool valid = !((j == 0 && s == 0) || (j == 2 && s == S_ - 1));
    float d = 0.f;
    if (valid) {
      const int tj = t + j - 1;
      bf16x8 y8 = *(const bf16x8*)&yrow[h * 512 + lane * 8];
      bf16x8 x8 = *(const bf16x8*)&xb[(size_t)tj * D_ + lane * 8];
#pragma unroll
      for (int e = 0; e < 8; ++e) d += bits2f((u16)y8[e]) * bits2f((u16)x8[e]);
    }
    for (int m = 32; m >= 1; m >>= 1) d += __shfl_xor(d, m);
    if (lane == 0) sSc[h][j] = valid ? d : -1e30f;
  }
  __syncthreads();
  if (tid < 8) {
    const float scale = 0.044194173824159f;  // 1/sqrt(512)
    float s0 = sSc[tid][0], s1 = sSc[tid][1], s2 = sSc[tid][2];
    s0 = (s0 > -1e29f) ? s0 * scale : -1e30f;
    s1 = s1 * scale;
    s2 = (s2 > -1e29f) ? s2 * scale : -1e30f;
    float mx = fmaxf(s0, fmaxf(s1, s2));
    float p0 = (s0 > -1e29f) ? expf(s0 - mx) : 0.f;
    float p1 = expf(s1 - mx);
    float p2 = (s2 > -1e29f) ? expf(s2 - mx) : 0.f;
    float inv = 1.f / (p0 + p1 + p2);
    sP[tid][0] = p0 * inv; sP[tid][1] = p1 * inv; sP[tid][2] = p2 * inv;
  }
  __syncthreads();
  // stencil over Z: thread tid -> output dims d0, d0+1
  const int d0 = tid * 2;
  const int tm = t - (s > 0 ? 1 : 0);
  const int tp = t + (s < S_ - 1 ? 1 : 0);
  const int trow[3] = {tm, t, tp};
  float a0 = 0.f, a1 = 0.f;
#pragma unroll
  for (int j = 0; j < 3; ++j) {
    const u16* zr = yz + (size_t)trow[j] * 8192 + 4096;
#pragma unroll
    for (int h = 0; h < 8; ++h) {
      const float p = sP[h][j];
      unsigned zz = *(const unsigned*)&zr[h * 512 + d0];
      a0 += p * bits2f((u16)(zz & 0xffffu));
      a1 += p * bits2f((u16)(zz >> 16));
    }
  }
  // residual + bo, then LN over the 512-dim row held across the block
  const size_t base = (size_t)t * D_;
  float2 xv = ((const float2*)(xres + base))[tid];
  float2 bv2 = ((const float2*)bo)[tid];
  float y0 = xv.x + a0 + bv2.x;
  float y1 = xv.y + a1 + bv2.y;
  float sum = y0 + y1, ssum = y0 * y0 + y1 * y1;
  for (int m = 32; m >= 1; m >>= 1) {
    sum += __shfl_xor(sum, m); ssum += __shfl_xor(ssum, m);
  }
  if (lane == 0) { red[wave] = sum; red[4 + wave] = ssum; }
  __syncthreads();
  sum = red[0] + red[1] + red[2] + red[3];
  ssum = red[4] + red[5] + red[6] + red[7];
  const float mean = sum * (1.f / D_);
  const float var = ssum * (1.f / D_) - mean * mean;
  const float rstd = rsqrtf(var + 1e-3f);
  float2 gv = ((const float2*)g1)[tid];
  float2 bev = ((const float2*)be1)[tid];
  float o0 = (y0 - mean) * rstd * gv.x + bev.x;
  float o1 = (y1 - mean) * rstd * gv.y + bev.y;
  float2 of; of.x = o0; of.y = o1;
  ((float2*)(out1f + base))[tid] = of;
  ushort2 ob; ob.x = f2bfbits(o0); ob.y = f2bfbits(o1);
  ((ushort2*)(out1b + base))[tid] = ob;
}

// ---------------------------------------------------------------------------
// y = xres + sum_p parts[p] (+bias); out = LN(y)*gamma+beta -> fp32 / bf16
// parts: part p row r at  parts + p*pstride + r*prowstride  (floats)
// ---------------------------------------------------------------------------
__global__ __launch_bounds__(256) void resid_ln(const float* __restrict__ xres,
                                                const float* __restrict__ parts,
                                                int nparts, size_t pstride,
                                                size_t prowstride,
                                                const float* __restrict__ bias,
                                                const float* __restrict__ gamma,
                                                const float* __restrict__ beta,
                                                float* __restrict__ outf,
                                                u16* __restrict__ outb) {
  const int row = blockIdx.x;
  const int tid = threadIdx.x;
  const size_t base = (size_t)row * D_;
  float2 xv = ((const float2*)(xres + base))[tid];
  float y0 = xv.x, y1 = xv.y;
  for (int p = 0; p < nparts; ++p) {
    const float* pr = parts + p * pstride + (size_t)row * prowstride;
    float2 pv = ((const float2*)pr)[tid];
    y0 += pv.x; y1 += pv.y;
  }
  if (bias) {
    float2 bv = ((const float2*)bias)[tid];
    y0 += bv.x; y1 += bv.y;
  }
  float s = y0 + y1, ss = y0 * y0 + y1 * y1;
  for (int m = 32; m >= 1; m >>= 1) { s += __shfl_xor(s, m); ss += __shfl_xor(ss, m); }
  __shared__ float red[8];
  const int wave = tid >> 6, lane = tid & 63;
  if (lane == 0) { red[wave] = s; red[4 + wave] = ss; }
  __syncthreads();
  s = red[0] + red[1] + red[2] + red[3];
  ss = red[4] + red[5] + red[6] + red[7];
  const float mean = s * (1.f / D_);
  const float var = ss * (1.f / D_) - mean * mean;
  const float rstd = rsqrtf(var + 1e-3f);
  float2 gv = ((const float2*)gamma)[tid];
  float2 bev = ((const float2*)beta)[tid];
  float o0 = (y0 - mean) * rstd * gv.x + bev.x;
  float o1 = (y1 - mean) * rstd * gv.y + bev.y;
  if (outf) { float2 of; of.x = o0; of.y = o1; ((float2*)(outf + base))[tid] = of; }
  if (outb) { ushort2 ob; ob.x = f2bfbits(o0); ob.y = f2bfbits(o1); ((ushort2*)(outb + base))[tid] = ob; }
}

// ---------------------------------------------------------------------------
extern "C" void kernel_launch(void* const* d_in, const int* in_sizes, int n_in,
                              void* d_out, int out_size, void* d_ws, size_t ws_size,
                              hipStream_t stream) {
  const float* x  = (const float*)d_in[0];
  const float* Wq = (const float*)d_in[1];
  const float* Wk = (const float*)d_in[3];
  const float* Wv = (const float*)d_in[5];
  const float* bv = (const float*)d_in[6];
  const float* Wo = (const float*)d_in[7];
  const float* bo = (const float*)d_in[8];
  const float* W1 = (const float*)d_in[9];
  const float* b1 = (const float*)d_in[10];
  const float* W2 = (const float*)d_in[11];
  const float* b2 = (const float*)d_in[12];
  const float* g1 = (const float*)d_in[13];
  const float* be1 = (const float*)d_in[14];
  const float* g2 = (const float*)d_in[15];
  const float* be2 = (const float*)d_in[16];
  float* out = (float*)d_out;

  char* w = (char*)d_ws;
  size_t o = 0;
  auto nxt = [&](size_t bytes) -> char* {
    char* p = w + o;
    o += (bytes + 255) & ~(size_t)255;
    return p;
  };
  u16* xb     = (u16*)nxt((size_t)NT * D_ * 2);        // 8.4MB
  u16* wq_nt  = (u16*)nxt((size_t)D_ * HK * 2);        // 4.2MB [D][HK]
  u16* wk_nt  = (u16*)nxt((size_t)D_ * HK * 2);        // 4.2MB
  u16* wv_nt  = (u16*)nxt((size_t)D_ * HK * 2);        // 4.2MB
  u16* wot    = (u16*)nxt((size_t)D_ * HK * 2);        // 4.2MB
  u16* w1t    = (u16*)nxt((size_t)F_ * D_ * 2);        // 2.1MB
  u16* w2t    = (u16*)nxt((size_t)D_ * F_ * 2);        // 2.1MB
  u16* mg     = (u16*)nxt((size_t)8192 * 512 * 2);     // 8.4MB [M^T | G^T]
  float* biascat = (float*)nxt((size_t)8192 * 4);
  u16* yz     = (u16*)nxt((size_t)NT * 8192 * 2);      // 134.2MB [Y|Z] per row
  float* out1f = (float*)nxt((size_t)NT * D_ * 4);     // 16.8MB
  u16* out1b   = (u16*)nxt((size_t)NT * D_ * 2);       // 8.4MB
  // aliases inside yz (live ranges disjoint):
  //  hb: FFN1 out [NT][F] bf16 at yz+0 (yz fully dead after attn_ln)
  u16* hb = (u16*)yz;
  //  ffnP: FFN2 partials [2][NT][D] f32 at yz bytes [64MB, 97.6MB)
  float* ffnP = (float*)((char*)yz + 67108864);

  // --- prep: transposes + converts + cbias (one launch, r12 version) ---
  prep_all<<<dim3(15360), 256, 0, stream>>>(Wq, Wk, Wv, Wo, W1, W2, bv, x,
                                            wq_nt, wk_nt, wv_nt, wot, w1t, w2t,
                                            biascat, xb);

  // --- MG-pre (16 batched 512^3):
  //  z<8:  mg[z*512+d'][d]  = sum_k Wk[d',(z,k)]·Wq[d,(z,k)]   (M_h^T)
  //  z>=8: mg[z*512+d'][d]  = sum_k Wo[(h,k),d']·Wv[d,(h,k)]   (G_h^T)
  gemm128d<0, 0, 1, 1><<<dim3(4, 4, 16), 256, 0, stream>>>(
      wk_nt, HK, 512, wq_nt, HK, 512, wot, wv_nt, 8,
      nullptr, nullptr, 0, mg, 512, (size_t)512 * 512, 512);

  // --- YZ: yz[t] = [ x@M_h | x@G_h + c ]  (one N=8192 GEMM) ---
  gemm128d<1, 0, 1, 0><<<dim3(64, 64, 1), 256, 0, stream>>>(
      xb, D_, 0, mg, 512, 0, nullptr, nullptr, 0, biascat,
      nullptr, 0, yz, 8192, 0, 512);

  // --- attn + residual + LN1 fused -> out1f / out1b (XCD-chunked t) ---
  attn_ln<<<dim3(NT), 256, 0, stream>>>(yz, xb, x, bo, g1, be1, out1f, out1b);

  // --- FFN1: hb = gelu(out1 @ W1 + b1) ---
  gemm128d<1, 1, 1, 0><<<dim3(64, 16, 1), 256, 0, stream>>>(
      out1b, D_, 0, w1t, D_, 0, nullptr, nullptr, 0, b1,
      nullptr, 0, hb, F_, 0, 512);

  // --- FFN2: ffnP[z] = hb @ W2 (split-K=2; b2 folded into LN2) ---
  gemm128d<0, 0, 0, 0><<<dim3(64, 4, 2), 256, 0, stream>>>(
      hb, F_, 0, w2t, F_, 0, nullptr, nullptr, 0, nullptr,
      ffnP, (size_t)NT * D_, nullptr, D_, 0, 1024);

  // --- LN2: out = LN(out1 + ffn + b2) ---
  resid_ln<<<dim3(NT), 256, 0, stream>>>(out1f, ffnP, 2, (size_t)NT * D_, D_, b2,
                                         g2, be2, out, nullptr);

  (void)in_sizes; (void)n_in; (void)out_size; (void)ws_size;
}